// Round 9
// baseline (423.846 us; speedup 1.0000x reference)
//
#include <hip/hip_runtime.h>
#include <hip/hip_bf16.h>

// Two-layer RGCN (mean aggregation per relation) for MI355X.
// Round 9: operand-swapped fused kernel. A = weight fragments (L2-hot global,
// reloaded per wave), B = gathered per-node segment means. No LDS, no
// barriers -> latency hidden by TLP; stores become float4/ushort4 per node
// row. L1 col-split 2x for extra waves. Verified D mapping:
// D(c,r,g) = sum_k P_content(4g+r) * Q_content(c), P = first operand.
// CSR (node-major), converts as round 8. Round-7 ref: 258.8 us, L1 87.8 us.

#define D_IN 128
#define NREL 8

typedef short bf16x8 __attribute__((ext_vector_type(8)));
typedef float f32x4 __attribute__((ext_vector_type(4)));

__device__ __forceinline__ ushort cvbf(float f) {  // f32 -> bf16 RNE
    unsigned u = __float_as_uint(f);
    return (ushort)((u + 0x7FFFu + ((u >> 16) & 1u)) >> 16);
}
__device__ __forceinline__ float bflo(unsigned v) { return __uint_as_float(v << 16); }
__device__ __forceinline__ float bfhi(unsigned v) { return __uint_as_float(v & 0xFFFF0000u); }

// ---------------- f32 -> bf16 convert (4 elems/thread) ----------------
__global__ void to_bf16_kernel(const float* __restrict__ in,
                               ushort* __restrict__ out, int n4) {
    int i = blockIdx.x * blockDim.x + threadIdx.x;
    if (i >= n4) return;
    float4 v = ((const float4*)in)[i];
    ushort4 o;
    o.x = cvbf(v.x); o.y = cvbf(v.y); o.z = cvbf(v.z); o.w = cvbf(v.w);
    ((ushort4*)out)[i] = o;
}

// -------- weight pre-transform: bf16 W^T: Wt[s][n][k], stride 128 ----------
__global__ void wt_transform_kernel(const float* __restrict__ W,
                                    const float* __restrict__ root,
                                    ushort* __restrict__ Wt, int NCOLS) {
    int i = blockIdx.x * blockDim.x + threadIdx.x;
    int tot = (NREL + 1) * D_IN * NCOLS;
    if (i >= tot) return;
    int s = i / (D_IN * NCOLS);
    int r = i - s * D_IN * NCOLS;
    int k = r / NCOLS;
    int n = r - k * NCOLS;
    float v = (s < NREL) ? W[(size_t)s * D_IN * NCOLS + (size_t)k * NCOLS + n]
                         : root[(size_t)k * NCOLS + n];
    Wt[((size_t)s * NCOLS + n) * D_IN + k] = cvbf(v);
}

// ---------------- CSR build (seg = dst*8 + et, node-major) ----------------
__global__ void count_kernel(const int* __restrict__ dst,
                             const int* __restrict__ et,
                             int* __restrict__ cnt, int E, int N) {
    int e = blockIdx.x * blockDim.x + threadIdx.x;
    if (e < E) atomicAdd(&cnt[dst[e] * NREL + et[e]], 1);
}

__global__ void scan_block_sum(const int* __restrict__ cnt,
                               int* __restrict__ bsum, int nseg) {
    __shared__ int s[256];
    int base = blockIdx.x * 1024 + threadIdx.x * 4;
    int v = 0;
#pragma unroll
    for (int i = 0; i < 4; ++i) {
        int idx = base + i;
        if (idx < nseg) v += cnt[idx];
    }
    s[threadIdx.x] = v;
    __syncthreads();
    for (int off = 128; off > 0; off >>= 1) {
        if (threadIdx.x < off) s[threadIdx.x] += s[threadIdx.x + off];
        __syncthreads();
    }
    if (threadIdx.x == 0) bsum[blockIdx.x] = s[0];
}

__global__ void scan_bsum(int* __restrict__ bsum, int nb) {
    __shared__ int s[512];
    int t = threadIdx.x;
    int my = (t < nb) ? bsum[t] : 0;
    s[t] = my;
    __syncthreads();
    for (int off = 1; off < 512; off <<= 1) {
        int v = (t >= off) ? s[t - off] : 0;
        __syncthreads();
        s[t] += v;
        __syncthreads();
    }
    if (t < nb) bsum[t] = s[t] - my;  // exclusive
}

__global__ void scan_write(const int* __restrict__ cnt,
                           const int* __restrict__ bsum,
                           int* __restrict__ off, int nseg) {
    __shared__ int s[256];
    int t = threadIdx.x;
    int base = blockIdx.x * 1024 + t * 4;
    int v[4];
    int sum = 0;
#pragma unroll
    for (int i = 0; i < 4; ++i) {
        int idx = base + i;
        v[i] = (idx < nseg) ? cnt[idx] : 0;
        sum += v[i];
    }
    s[t] = sum;
    __syncthreads();
    int my = sum;
    for (int o = 1; o < 256; o <<= 1) {
        int x = (t >= o) ? s[t - o] : 0;
        __syncthreads();
        s[t] += x;
        __syncthreads();
    }
    int pre = s[t] - my + bsum[blockIdx.x];
#pragma unroll
    for (int i = 0; i < 4; ++i) {
        int idx = base + i;
        if (idx < nseg) {
            off[idx] = pre;
            pre += v[i];
        }
    }
}

__global__ void bucket_kernel(const int* __restrict__ src,
                              const int* __restrict__ dst,
                              const int* __restrict__ et,
                              int* __restrict__ off,
                              int* __restrict__ sids, int E, int N) {
    int e = blockIdx.x * blockDim.x + threadIdx.x;
    if (e < E) {
        int seg = dst[e] * NREL + et[e];
        int pos = atomicAdd(&off[seg], 1);
        sids[pos] = src[e];
    }
}

// ------------- fused aggregate + MFMA GEMM (no LDS, no barriers) -----------
// out[n][j] = bias[j] + feat[n]@root[:,j]
//           + sum_r mean_{e in seg(n,r)} feat[src_e] @ W[r][:,j]
// Wave handles 16 nodes x 64 output cols. A = W^T fragment (from global),
// B = gathered feature mean fragment. Lane (c,g), reg r of tile t holds
// out[node rb+c][colbase + t*16 + 4g + r].
template <bool RELU, bool OUTBF16>
__global__ __launch_bounds__(256) void fused_gemm_kernel(
    const ushort* __restrict__ feat,   // [N][128] bf16
    const int* __restrict__ sids,      // [E] src ids grouped by (dst*8+et)
    const int* __restrict__ endoff,    // [N*8] end offsets
    const ushort* __restrict__ Wt,     // [R+1][NCOLS][128] bf16 (W^T)
    const float* __restrict__ bias,    // [NCOLS]
    void* __restrict__ outp,           // [N][NCOLS] bf16 or f32
    int N, int NCOLS) {
    const int tid = threadIdx.x;
    const int wave = tid >> 6;
    const int lane = tid & 63;
    const int c = lane & 15;   // node index within 16-row group
    const int g = lane >> 4;   // k-group
    const int row = blockIdx.x * 64 + wave * 16 + c;  // this lane's node
    const int arow = min(row, N - 1);
    const int colbase = blockIdx.y * 64;

    // 9 segment boundaries for this node (contiguous run, node-major CSR)
    int so[9];
    {
        int b = arow * NREL;
        so[0] = (b == 0) ? 0 : endoff[b - 1];
#pragma unroll
        for (int s = 1; s <= NREL; ++s) so[s] = endoff[b + s - 1];
    }

    f32x4 acc[4];
#pragma unroll
    for (int t = 0; t < 4; ++t) acc[t] = (f32x4){0.f, 0.f, 0.f, 0.f};

    const ushort* myrow = feat + (size_t)arow * D_IN + 8 * g;

    // ---- root segment first (no gather dependency) ----
    {
        bf16x8 bfrag[4];
#pragma unroll
        for (int q = 0; q < 4; ++q) bfrag[q] = *(const bf16x8*)(myrow + 32 * q);
        const ushort* wseg = Wt + ((size_t)NREL * NCOLS + colbase) * D_IN;
#pragma unroll
        for (int q = 0; q < 4; ++q)
#pragma unroll
            for (int t = 0; t < 4; ++t) {
                bf16x8 w = *(const bf16x8*)(wseg + (size_t)(t * 16 + c) * D_IN + q * 32 + 8 * g);
                acc[t] = __builtin_amdgcn_mfma_f32_16x16x32_bf16(w, bfrag[q], acc[t], 0, 0, 0);
            }
    }

    // ---- 8 relation segments: gather mean, then MFMA ----
    for (int s = 0; s < NREL; ++s) {
        int start = so[s], end = so[s + 1];
        int deg = end - start;
        float ac[4][8];
#pragma unroll
        for (int q = 0; q < 4; ++q)
#pragma unroll
            for (int j = 0; j < 8; ++j) ac[q][j] = 0.f;
        for (int e = start; e < end; ++e) {
            int id = sids[e];
            const ushort* fr = feat + (size_t)id * D_IN + 8 * g;
#pragma unroll
            for (int q = 0; q < 4; ++q) {
                uint4 v = *(const uint4*)(fr + 32 * q);
                ac[q][0] += bflo(v.x); ac[q][1] += bfhi(v.x);
                ac[q][2] += bflo(v.y); ac[q][3] += bfhi(v.y);
                ac[q][4] += bflo(v.z); ac[q][5] += bfhi(v.z);
                ac[q][6] += bflo(v.w); ac[q][7] += bfhi(v.w);
            }
        }
        float inv = (deg > 0) ? 1.0f / (float)deg : 0.0f;
        bf16x8 bfrag[4];
#pragma unroll
        for (int q = 0; q < 4; ++q) {
            uint4 pk;
            pk.x = (unsigned)cvbf(ac[q][0] * inv) | ((unsigned)cvbf(ac[q][1] * inv) << 16);
            pk.y = (unsigned)cvbf(ac[q][2] * inv) | ((unsigned)cvbf(ac[q][3] * inv) << 16);
            pk.z = (unsigned)cvbf(ac[q][4] * inv) | ((unsigned)cvbf(ac[q][5] * inv) << 16);
            pk.w = (unsigned)cvbf(ac[q][6] * inv) | ((unsigned)cvbf(ac[q][7] * inv) << 16);
            bfrag[q] = *(bf16x8*)&pk;
        }
        const ushort* wseg = Wt + ((size_t)s * NCOLS + colbase) * D_IN;
#pragma unroll
        for (int q = 0; q < 4; ++q)
#pragma unroll
            for (int t = 0; t < 4; ++t) {
                bf16x8 w = *(const bf16x8*)(wseg + (size_t)(t * 16 + c) * D_IN + q * 32 + 8 * g);
                acc[t] = __builtin_amdgcn_mfma_f32_16x16x32_bf16(w, bfrag[q], acc[t], 0, 0, 0);
            }
    }

    // ---- epilogue: node-row vectorized stores ----
    if (row < N) {
#pragma unroll
        for (int t = 0; t < 4; ++t) {
            int colb = colbase + t * 16 + 4 * g;
            float4 bv = *(const float4*)(bias + colb);
            float v0 = acc[t][0] + bv.x;
            float v1 = acc[t][1] + bv.y;
            float v2 = acc[t][2] + bv.z;
            float v3 = acc[t][3] + bv.w;
            if (RELU) {
                v0 = fmaxf(v0, 0.f); v1 = fmaxf(v1, 0.f);
                v2 = fmaxf(v2, 0.f); v3 = fmaxf(v3, 0.f);
            }
            if (OUTBF16) {
                ushort4 o;
                o.x = cvbf(v0); o.y = cvbf(v1); o.z = cvbf(v2); o.w = cvbf(v3);
                *(ushort4*)((ushort*)outp + (size_t)row * NCOLS + colb) = o;
            } else {
                *(float4*)((float*)outp + (size_t)row * NCOLS + colb) =
                    make_float4(v0, v1, v2, v3);
            }
        }
    }
}

extern "C" void kernel_launch(void* const* d_in, const int* in_sizes, int n_in,
                              void* d_out, int out_size, void* d_ws, size_t ws_size,
                              hipStream_t stream) {
    const float* x = (const float*)d_in[0];
    const int* ei = (const int*)d_in[1];
    const int* et = (const int*)d_in[2];
    const float* W1 = (const float*)d_in[3];
    const float* root1 = (const float*)d_in[4];
    const float* bias1 = (const float*)d_in[5];
    const float* W2 = (const float*)d_in[6];
    const float* root2 = (const float*)d_in[7];
    const float* bias2 = (const float*)d_in[8];
    float* out = (float*)d_out;

    const int N = in_sizes[0] / D_IN;  // 50000
    const int E = in_sizes[2];         // 800000
    const int* src = ei;
    const int* dst = ei + E;
    const int NSEG = NREL * N;            // 400000
    const int NB = (NSEG + 1023) / 1024;  // 391 (<=512 for scan_bsum)

    // workspace layout (all 16B-aligned)
    ushort* xb = (ushort*)d_ws;                      // N*128 bf16 = 12.8 MB
    ushort* hb = xb + (size_t)N * D_IN;              // N*128 bf16 = 12.8 MB
    ushort* wt1 = hb + (size_t)N * D_IN;             // 9*128*128 bf16
    ushort* wt2 = wt1 + (size_t)(NREL + 1) * D_IN * D_IN;  // 9*64*128 bf16
    int* off = (int*)(wt2 + (size_t)(NREL + 1) * 64 * D_IN);  // NSEG ints
    int* sids = off + NSEG;                          // E ints
    int* cnt = sids + E;                             // NSEG ints
    int* bsum = cnt + NSEG;                          // NB ints

    // ---- input conversions / weight transforms (independent) ----
    to_bf16_kernel<<<(N * D_IN / 4 + 255) / 256, 256, 0, stream>>>(x, xb, N * D_IN / 4);
    wt_transform_kernel<<<((NREL + 1) * D_IN * 128 + 255) / 256, 256, 0, stream>>>(
        W1, root1, wt1, 128);
    wt_transform_kernel<<<((NREL + 1) * D_IN * 64 + 255) / 256, 256, 0, stream>>>(
        W2, root2, wt2, 64);

    // ---- CSR build (edge set identical for both layers) ----
    hipMemsetAsync(cnt, 0, (size_t)NSEG * sizeof(int), stream);
    count_kernel<<<(E + 255) / 256, 256, 0, stream>>>(dst, et, cnt, E, N);
    scan_block_sum<<<NB, 256, 0, stream>>>(cnt, bsum, NSEG);
    scan_bsum<<<1, 512, 0, stream>>>(bsum, NB);
    scan_write<<<NB, 256, 0, stream>>>(cnt, bsum, off, NSEG);
    bucket_kernel<<<(E + 255) / 256, 256, 0, stream>>>(src, dst, et, off, sids, E, N);
    // off[] now holds END offsets per segment.

    const int rowBlocks = (N + 63) / 64;

    // ---- layer 1 (128 cols, col-split 2x) ----
    fused_gemm_kernel<true, true><<<dim3(rowBlocks, 2), 256, 0, stream>>>(
        xb, sids, off, wt1, bias1, hb, N, 128);

    // ---- layer 2 (64 cols) ----
    fused_gemm_kernel<false, false><<<dim3(rowBlocks, 1), 256, 0, stream>>>(
        hb, sids, off, wt2, bias2, out, N, 64);
}

// Round 10
// 335.332 us; speedup vs baseline: 1.2640x; 1.2640x over previous
//
#include <hip/hip_runtime.h>
#include <hip/hip_bf16.h>

// Two-layer RGCN (mean aggregation per relation) for MI355X.
// Round 10: round-7 structure (weights staged in single 32KB LDS buffer,
// per-wave 16-node gather into A-fragments) + latency fixes:
//  - depth-2 software pipeline over the per-segment edge list
//  - BUILD(rel i) overlapped with MFMA(previous segment); root segment first
//  - Bt row stride 272 B (odd*16B -> 4 lanes/bank-quad, b128 floor)
// CSR (node-major seg = dst*8+et), converts unchanged. Best so far: 258.8 us.

#define D_IN 128
#define NREL 8
#define BTSTRIDE 136  // ushorts per padded B row (136*2 = 272 B = 17*16B, odd quads)

typedef short bf16x8 __attribute__((ext_vector_type(8)));
typedef float f32x4 __attribute__((ext_vector_type(4)));

__device__ __forceinline__ ushort cvbf(float f) {  // f32 -> bf16 RNE
    unsigned u = __float_as_uint(f);
    return (ushort)((u + 0x7FFFu + ((u >> 16) & 1u)) >> 16);
}
__device__ __forceinline__ float bflo(unsigned v) { return __uint_as_float(v << 16); }
__device__ __forceinline__ float bfhi(unsigned v) { return __uint_as_float(v & 0xFFFF0000u); }

// ---------------- f32 -> bf16 convert (4 elems/thread) ----------------
__global__ void to_bf16_kernel(const float* __restrict__ in,
                               ushort* __restrict__ out, int n4) {
    int i = blockIdx.x * blockDim.x + threadIdx.x;
    if (i >= n4) return;
    float4 v = ((const float4*)in)[i];
    ushort4 o;
    o.x = cvbf(v.x); o.y = cvbf(v.y); o.z = cvbf(v.z); o.w = cvbf(v.w);
    ((ushort4*)out)[i] = o;
}

// -------- weight pre-transform: bf16 W^T, padded row stride ---------------
// Wt[s][n][k] at ((s*NCOLS + n)*BTSTRIDE + k); k in [0,128). s==NREL: root.
__global__ void wt_transform_kernel(const float* __restrict__ W,
                                    const float* __restrict__ root,
                                    ushort* __restrict__ Wt, int NCOLS) {
    int i = blockIdx.x * blockDim.x + threadIdx.x;
    int tot = (NREL + 1) * D_IN * NCOLS;
    if (i >= tot) return;
    int s = i / (D_IN * NCOLS);
    int r = i - s * D_IN * NCOLS;
    int k = r / NCOLS;
    int n = r - k * NCOLS;
    float v = (s < NREL) ? W[(size_t)s * D_IN * NCOLS + (size_t)k * NCOLS + n]
                         : root[(size_t)k * NCOLS + n];
    Wt[((size_t)s * NCOLS + n) * BTSTRIDE + k] = cvbf(v);
}

// ---------------- CSR build (seg = dst*8 + et, node-major) ----------------
__global__ void count_kernel(const int* __restrict__ dst,
                             const int* __restrict__ et,
                             int* __restrict__ cnt, int E, int N) {
    int e = blockIdx.x * blockDim.x + threadIdx.x;
    if (e < E) atomicAdd(&cnt[dst[e] * NREL + et[e]], 1);
}

__global__ void scan_block_sum(const int* __restrict__ cnt,
                               int* __restrict__ bsum, int nseg) {
    __shared__ int s[256];
    int base = blockIdx.x * 1024 + threadIdx.x * 4;
    int v = 0;
#pragma unroll
    for (int i = 0; i < 4; ++i) {
        int idx = base + i;
        if (idx < nseg) v += cnt[idx];
    }
    s[threadIdx.x] = v;
    __syncthreads();
    for (int off = 128; off > 0; off >>= 1) {
        if (threadIdx.x < off) s[threadIdx.x] += s[threadIdx.x + off];
        __syncthreads();
    }
    if (threadIdx.x == 0) bsum[blockIdx.x] = s[0];
}

__global__ void scan_bsum(int* __restrict__ bsum, int nb) {
    __shared__ int s[512];
    int t = threadIdx.x;
    int my = (t < nb) ? bsum[t] : 0;
    s[t] = my;
    __syncthreads();
    for (int off = 1; off < 512; off <<= 1) {
        int v = (t >= off) ? s[t - off] : 0;
        __syncthreads();
        s[t] += v;
        __syncthreads();
    }
    if (t < nb) bsum[t] = s[t] - my;  // exclusive
}

__global__ void scan_write(const int* __restrict__ cnt,
                           const int* __restrict__ bsum,
                           int* __restrict__ off, int nseg) {
    __shared__ int s[256];
    int t = threadIdx.x;
    int base = blockIdx.x * 1024 + t * 4;
    int v[4];
    int sum = 0;
#pragma unroll
    for (int i = 0; i < 4; ++i) {
        int idx = base + i;
        v[i] = (idx < nseg) ? cnt[idx] : 0;
        sum += v[i];
    }
    s[t] = sum;
    __syncthreads();
    int my = sum;
    for (int o = 1; o < 256; o <<= 1) {
        int x = (t >= o) ? s[t - o] : 0;
        __syncthreads();
        s[t] += x;
        __syncthreads();
    }
    int pre = s[t] - my + bsum[blockIdx.x];
#pragma unroll
    for (int i = 0; i < 4; ++i) {
        int idx = base + i;
        if (idx < nseg) {
            off[idx] = pre;
            pre += v[i];
        }
    }
}

__global__ void bucket_kernel(const int* __restrict__ src,
                              const int* __restrict__ dst,
                              const int* __restrict__ et,
                              int* __restrict__ off,
                              int* __restrict__ sids, int E, int N) {
    int e = blockIdx.x * blockDim.x + threadIdx.x;
    if (e < E) {
        int seg = dst[e] * NREL + et[e];
        int pos = atomicAdd(&off[seg], 1);
        sids[pos] = src[e];
    }
}

// ---------------- fused aggregate + MFMA GEMM (pipelined) ----------------
// out[n][j] = bias[j] + feat[n]@root[:,j]
//           + sum_r mean_{e in seg(n,r)} feat[src_e] @ W[r][:,j]
// Segment order: root first (no gather), then relations 0..7; BUILD of
// relation i overlaps the MFMAs of the previous segment.
template <int NCOLS, bool RELU, bool OUTBF16>
__global__ __launch_bounds__(256) void fused_gemm_kernel(
    const ushort* __restrict__ feat,   // [N][128] bf16
    const int* __restrict__ sids,      // [E] src ids grouped by (dst*8+et)
    const int* __restrict__ endoff,    // [N*8] end offsets
    const ushort* __restrict__ Wt,     // [R+1][NCOLS][BTSTRIDE] bf16 (W^T)
    const float* __restrict__ bias,    // [NCOLS]
    void* __restrict__ outp,           // [N][NCOLS] bf16 or f32
    int N) {
    constexpr int NT = NCOLS / 16;                 // 16x16 col-tiles per wave
    constexpr int SEGU = NCOLS * BTSTRIDE / 8;     // uint4 per B segment
    __shared__ __align__(16) ushort Bt[NCOLS * BTSTRIDE];

    const int tid = threadIdx.x;
    const int wave = tid >> 6;
    const int lane = tid & 63;
    const int c = lane & 15;   // A-row / D-col within tile
    const int g = lane >> 4;   // k-group
    const int rb = blockIdx.x * 64 + wave * 16;
    const int arow = min(rb + c, N - 1);  // clamped; stores guarded

    f32x4 acc[NT];
#pragma unroll
    for (int t = 0; t < NT; ++t) acc[t] = (f32x4){0.f, 0.f, 0.f, 0.f};

    const ushort* myrow = feat + (size_t)arow * D_IN + 8 * g;

    bf16x8 aC[4], aN[4];

#define ACCQ(Q, V)                                        \
    ac[Q][0] += bflo((V).x); ac[Q][1] += bfhi((V).x);     \
    ac[Q][2] += bflo((V).y); ac[Q][3] += bfhi((V).y);     \
    ac[Q][4] += bflo((V).z); ac[Q][5] += bfhi((V).z);     \
    ac[Q][6] += bflo((V).w); ac[Q][7] += bfhi((V).w)

    // depth-2 pipelined gather of relation R's segment mean into DST
#define BUILD_REL(R, DST)                                                     \
    do {                                                                      \
        int _b = arow * NREL + (R);                                           \
        int _st = (_b == 0) ? 0 : endoff[_b - 1];                             \
        int _en = endoff[_b];                                                 \
        int _deg = _en - _st;                                                 \
        float ac[4][8];                                                       \
        _Pragma("unroll") for (int q = 0; q < 4; ++q)                         \
            _Pragma("unroll") for (int j = 0; j < 8; ++j) ac[q][j] = 0.f;     \
        uint4 c0, c1, c2, c3, n0, n1, n2, n3;                                 \
        if (_deg > 0) {                                                       \
            const ushort* fr = feat + (size_t)sids[_st] * D_IN + 8 * g;       \
            c0 = *(const uint4*)(fr);      c1 = *(const uint4*)(fr + 32);     \
            c2 = *(const uint4*)(fr + 64); c3 = *(const uint4*)(fr + 96);     \
        }                                                                     \
        for (int e = _st; e < _en; ++e) {                                     \
            if (e + 1 < _en) {                                                \
                const ushort* fr = feat + (size_t)sids[e + 1] * D_IN + 8 * g; \
                n0 = *(const uint4*)(fr);      n1 = *(const uint4*)(fr + 32); \
                n2 = *(const uint4*)(fr + 64); n3 = *(const uint4*)(fr + 96); \
            }                                                                 \
            ACCQ(0, c0); ACCQ(1, c1); ACCQ(2, c2); ACCQ(3, c3);               \
            c0 = n0; c1 = n1; c2 = n2; c3 = n3;                               \
        }                                                                     \
        float inv = (_deg > 0) ? 1.0f / (float)_deg : 0.0f;                   \
        _Pragma("unroll") for (int q = 0; q < 4; ++q) {                       \
            uint4 pk;                                                         \
            pk.x = (unsigned)cvbf(ac[q][0] * inv) |                           \
                   ((unsigned)cvbf(ac[q][1] * inv) << 16);                    \
            pk.y = (unsigned)cvbf(ac[q][2] * inv) |                           \
                   ((unsigned)cvbf(ac[q][3] * inv) << 16);                    \
            pk.z = (unsigned)cvbf(ac[q][4] * inv) |                           \
                   ((unsigned)cvbf(ac[q][5] * inv) << 16);                    \
            pk.w = (unsigned)cvbf(ac[q][6] * inv) |                           \
                   ((unsigned)cvbf(ac[q][7] * inv) << 16);                    \
            DST[q] = *(bf16x8*)&pk;                                           \
        }                                                                     \
    } while (0)

#define STAGE(S)                                                              \
    do {                                                                      \
        const uint4* srcw = (const uint4*)(Wt + (size_t)(S)*NCOLS * BTSTRIDE);\
        uint4* dstw = (uint4*)Bt;                                             \
        for (int i = tid; i < SEGU; i += 256) dstw[i] = srcw[i];              \
    } while (0)

    // prologue: aC = root-row fragments (no gather); stage root tile
#pragma unroll
    for (int q = 0; q < 4; ++q) aC[q] = *(const bf16x8*)(myrow + 32 * q);
    STAGE(NREL);
    __syncthreads();

    for (int i = 0; i <= NREL; ++i) {
        if (i < NREL) BUILD_REL(i, aN);  // gather overlaps MFMAs below
#pragma unroll
        for (int q = 0; q < 4; ++q) {
#pragma unroll
            for (int t = 0; t < NT; ++t) {
                const ushort* bp = Bt + (t * 16 + c) * BTSTRIDE + q * 32 + 8 * g;
                bf16x8 b = *(const bf16x8*)bp;
                acc[t] = __builtin_amdgcn_mfma_f32_16x16x32_bf16(aC[q], b, acc[t], 0, 0, 0);
            }
        }
        __syncthreads();  // Bt consumption complete
        if (i < NREL) {
            STAGE(i);     // stage relation i's tile for next iteration
#pragma unroll
            for (int q = 0; q < 4; ++q) aC[q] = aN[q];
            __syncthreads();
        }
    }

    // epilogue: D layout col=lane&15, row=(lane>>4)*4+reg
#pragma unroll
    for (int t = 0; t < NT; ++t) {
        float bv = bias[t * 16 + c];
#pragma unroll
        for (int r = 0; r < 4; ++r) {
            int orow = rb + 4 * g + r;
            if (orow < N) {
                float v = acc[t][r] + bv;
                if (RELU) v = fmaxf(v, 0.0f);
                if (OUTBF16)
                    ((ushort*)outp)[(size_t)orow * NCOLS + t * 16 + c] = cvbf(v);
                else
                    ((float*)outp)[(size_t)orow * NCOLS + t * 16 + c] = v;
            }
        }
    }
#undef BUILD_REL
#undef STAGE
#undef ACCQ
}

extern "C" void kernel_launch(void* const* d_in, const int* in_sizes, int n_in,
                              void* d_out, int out_size, void* d_ws, size_t ws_size,
                              hipStream_t stream) {
    const float* x = (const float*)d_in[0];
    const int* ei = (const int*)d_in[1];
    const int* et = (const int*)d_in[2];
    const float* W1 = (const float*)d_in[3];
    const float* root1 = (const float*)d_in[4];
    const float* bias1 = (const float*)d_in[5];
    const float* W2 = (const float*)d_in[6];
    const float* root2 = (const float*)d_in[7];
    const float* bias2 = (const float*)d_in[8];
    float* out = (float*)d_out;

    const int N = in_sizes[0] / D_IN;  // 50000
    const int E = in_sizes[2];         // 800000
    const int* src = ei;
    const int* dst = ei + E;
    const int NSEG = NREL * N;            // 400000
    const int NB = (NSEG + 1023) / 1024;  // 391 (<=512 for scan_bsum)

    // workspace layout (all 16B-aligned)
    ushort* xb = (ushort*)d_ws;                      // N*128 bf16 = 12.8 MB
    ushort* hb = xb + (size_t)N * D_IN;              // N*128 bf16 = 12.8 MB
    ushort* wt1 = hb + (size_t)N * D_IN;             // 9*128*136 bf16
    ushort* wt2 = wt1 + (size_t)(NREL + 1) * D_IN * BTSTRIDE;  // 9*64*136
    int* off = (int*)(wt2 + (size_t)(NREL + 1) * 64 * BTSTRIDE);  // NSEG ints
    int* sids = off + NSEG;                          // E ints
    int* cnt = sids + E;                             // NSEG ints
    int* bsum = cnt + NSEG;                          // NB ints

    // ---- input conversions / weight transforms (independent) ----
    to_bf16_kernel<<<(N * D_IN / 4 + 255) / 256, 256, 0, stream>>>(x, xb, N * D_IN / 4);
    wt_transform_kernel<<<((NREL + 1) * D_IN * 128 + 255) / 256, 256, 0, stream>>>(
        W1, root1, wt1, 128);
    wt_transform_kernel<<<((NREL + 1) * D_IN * 64 + 255) / 256, 256, 0, stream>>>(
        W2, root2, wt2, 64);

    // ---- CSR build (edge set identical for both layers) ----
    hipMemsetAsync(cnt, 0, (size_t)NSEG * sizeof(int), stream);
    count_kernel<<<(E + 255) / 256, 256, 0, stream>>>(dst, et, cnt, E, N);
    scan_block_sum<<<NB, 256, 0, stream>>>(cnt, bsum, NSEG);
    scan_bsum<<<1, 512, 0, stream>>>(bsum, NB);
    scan_write<<<NB, 256, 0, stream>>>(cnt, bsum, off, NSEG);
    bucket_kernel<<<(E + 255) / 256, 256, 0, stream>>>(src, dst, et, off, sids, E, N);
    // off[] now holds END offsets per segment.

    const int gemmBlocks = (N + 63) / 64;

    // ---- layer 1 (fused aggregate+GEMM) ----
    fused_gemm_kernel<128, true, true><<<gemmBlocks, 256, 0, stream>>>(
        xb, sids, off, wt1, bias1, hb, N);

    // ---- layer 2 ----
    fused_gemm_kernel<64, false, false><<<gemmBlocks, 256, 0, stream>>>(
        hb, sids, off, wt2, bias2, out, N);
}